// Round 1
// baseline (365.967 us; speedup 1.0000x reference)
//
#include <hip/hip_runtime.h>
#include <hip/hip_bf16.h>
#include <cstdint>
#include <cstddef>

// Problem constants (B,S,D,H = 2,2048,1024,16; DK=64)
#define BB 2
#define SS 2048
#define DD 1024
#define HH 16
#define DKK 64
#define MM (BB*SS)   // 4096 rows for the projection GEMMs

typedef __bf16 bf16x8 __attribute__((ext_vector_type(8)));
typedef float  f32x4  __attribute__((ext_vector_type(4)));

__device__ __forceinline__ unsigned short f2bf(float f) {
    unsigned u = __float_as_uint(f);
    u += 0x7FFF + ((u >> 16) & 1);   // round-to-nearest-even
    return (unsigned short)(u >> 16);
}

// ---------------- fp32 -> bf16 cast ----------------
__global__ __launch_bounds__(256) void cast_f32_bf16(const float* __restrict__ src,
                                                     unsigned short* __restrict__ dst, int n) {
    int i = (blockIdx.x * 256 + threadIdx.x) * 4;
    if (i < n) {
        float4 v = *reinterpret_cast<const float4*>(src + i);
        ushort4 o;
        o.x = f2bf(v.x); o.y = f2bf(v.y); o.z = f2bf(v.z); o.w = f2bf(v.w);
        *reinterpret_cast<ushort4*>(dst + i) = o;
    }
}

// ---------------- GEMM: C[m,n] = sum_k A[m,k] * W[n,k]  (both bf16 row-major) ----------------
// mode 0/1: RoPE epilogue, write bf16 [B,H,S,DK]   (Q / K)
// mode 2  : no RoPE,      write bf16 [B,H,S,DK]   (V)
// mode 3  : write fp32 [M,N] flat                  (output projection)
__global__ __launch_bounds__(256) void gemm_bt(const unsigned short* __restrict__ A,
                                               const unsigned short* __restrict__ W,
                                               void* __restrict__ outp, int mode) {
    __shared__ unsigned short As[128 * 32];
    __shared__ unsigned short Ws[128 * 32];
    const int tid  = threadIdx.x;
    const int wave = tid >> 6, lane = tid & 63;
    const int quad = lane >> 4, l16 = lane & 15;
    const int wm = wave >> 1, wn = wave & 1;
    const int m0 = blockIdx.y * 128, n0 = blockIdx.x * 128;
    const int K = DD;

    f32x4 acc[4][4];
    for (int i = 0; i < 4; i++)
        for (int j = 0; j < 4; j++) acc[i][j] = f32x4{0.f, 0.f, 0.f, 0.f};

    for (int k0 = 0; k0 < K; k0 += 32) {
        __syncthreads();
        for (int c = tid; c < 512; c += 256) {
            int row = c >> 2, col = (c & 3) << 3;
            *reinterpret_cast<float4*>(As + row * 32 + col) =
                *reinterpret_cast<const float4*>(A + (size_t)(m0 + row) * K + k0 + col);
            *reinterpret_cast<float4*>(Ws + row * 32 + col) =
                *reinterpret_cast<const float4*>(W + (size_t)(n0 + row) * K + k0 + col);
        }
        __syncthreads();
        bf16x8 af[4], bfb[4];
        for (int i = 0; i < 4; i++)
            af[i] = *reinterpret_cast<const bf16x8*>(As + (wm * 64 + i * 16 + l16) * 32 + quad * 8);
        for (int j = 0; j < 4; j++)
            bfb[j] = *reinterpret_cast<const bf16x8*>(Ws + (wn * 64 + j * 16 + l16) * 32 + quad * 8);
        for (int i = 0; i < 4; i++)
            for (int j = 0; j < 4; j++)
                acc[i][j] = __builtin_amdgcn_mfma_f32_16x16x32_bf16(af[i], bfb[j], acc[i][j], 0, 0, 0);
    }

    const float L2T_OVER_DK = 13.287712379549449f / 64.0f;  // log2(10000)/64
    if (mode == 3) {
        float* Co = (float*)outp;
        for (int i = 0; i < 4; i++) {
            int mrow = m0 + wm * 64 + i * 16 + quad * 4;
            for (int j = 0; j < 4; j++) {
                int ncol = n0 + wn * 64 + j * 16 + l16;
                for (int r = 0; r < 4; r++)
                    Co[(size_t)(mrow + r) * DD + ncol] = acc[i][j][r];
            }
        }
    } else {
        unsigned short* Co = (unsigned short*)outp;
        const bool rope = (mode != 2);
        for (int i = 0; i < 4; i++) {
            int mrow = m0 + wm * 64 + i * 16 + quad * 4;
            for (int j = 0; j < 4; j++) {
                int ncol = n0 + wn * 64 + j * 16 + l16;
                int h = ncol >> 6, dk = ncol & 63;
                for (int r = 0; r < 4; r++) {
                    int m = mrow + r;
                    int b = m >> 11, s = m & 2047;
                    float v = acc[i][j][r];
                    float partner = __shfl_xor(v, 1, 64);  // lane^1 holds dk^1 (same RoPE pair)
                    float outv = v;
                    if (rope) {
                        float inv_freq = exp2f(-(float)(dk & ~1) * L2T_OVER_DK);
                        float ang = (float)s * inv_freq;
                        float sn, cs;
                        __sincosf(ang, &sn, &cs);
                        outv = v * cs + ((dk & 1) ? partner : -partner) * sn;
                    }
                    Co[((size_t)(b * HH + h) * SS + s) * DKK + dk] = f2bf(outv);
                }
            }
        }
    }
}

// ---------------- Flash attention (causal, online softmax) ----------------
// grid: (S/64 q-tiles, B*H). 256 thr = 4 waves; wave w owns q rows [q0+16w, q0+16w+16).
__global__ __launch_bounds__(256) void attn_kernel(const unsigned short* __restrict__ Qb,
                                                   const unsigned short* __restrict__ Kb,
                                                   const unsigned short* __restrict__ Vb,
                                                   unsigned short* __restrict__ attn) {
    __shared__ unsigned short Ks[64 * 72];      // K tile, row-major, stride 72 (pad: frag reads 2-way free)
    __shared__ unsigned short Vs[64 * 66];      // V tile, row-major, stride 66 (scalar reads conflict-free)
    __shared__ unsigned short Ps[4][16 * 72];   // per-wave P tile (C-layout -> A-layout round trip)

    const int tid  = threadIdx.x;
    const int wave = tid >> 6, lane = tid & 63;
    const int quad = lane >> 4, l16 = lane & 15;
    const int q0 = blockIdx.x * 64;
    const int bh = blockIdx.y;

    const unsigned short* Qg = Qb + (size_t)bh * SS * DKK;
    const unsigned short* Kg = Kb + (size_t)bh * SS * DKK;
    const unsigned short* Vg = Vb + (size_t)bh * SS * DKK;

    const int qrow = q0 + wave * 16 + l16;  // A-operand: m = lane&15
    bf16x8 qf0 = *reinterpret_cast<const bf16x8*>(Qg + (size_t)qrow * DKK + quad * 8);
    bf16x8 qf1 = *reinterpret_cast<const bf16x8*>(Qg + (size_t)qrow * DKK + 32 + quad * 8);

    f32x4 ao[4];
    for (int j = 0; j < 4; j++) ao[j] = f32x4{0.f, 0.f, 0.f, 0.f};
    float mrun[4] = {-1e30f, -1e30f, -1e30f, -1e30f};
    float lrun[4] = {0.f, 0.f, 0.f, 0.f};
    const float L2E = 1.4426950408889634f;

    for (int kv0 = 0; kv0 <= q0; kv0 += 64) {
        __syncthreads();   // previous iteration's PV reads of Vs done
        for (int c = tid; c < 512; c += 256) {
            int row = c >> 3, col = (c & 7) << 3;
            *reinterpret_cast<float4*>(Ks + row * 72 + col) =
                *reinterpret_cast<const float4*>(Kg + (size_t)(kv0 + row) * DKK + col);
            uint4 vv = *reinterpret_cast<const uint4*>(Vg + (size_t)(kv0 + row) * DKK + col);
            unsigned* vp = reinterpret_cast<unsigned*>(Vs + row * 66 + col);
            vp[0] = vv.x; vp[1] = vv.y; vp[2] = vv.z; vp[3] = vv.w;
        }
        __syncthreads();

        // S = Q K^T (16x64 per wave)
        f32x4 sc[4];
        for (int j = 0; j < 4; j++) {
            bf16x8 kf0 = *reinterpret_cast<const bf16x8*>(Ks + (j * 16 + l16) * 72 + quad * 8);
            bf16x8 kf1 = *reinterpret_cast<const bf16x8*>(Ks + (j * 16 + l16) * 72 + 32 + quad * 8);
            f32x4 s = f32x4{0.f, 0.f, 0.f, 0.f};
            s = __builtin_amdgcn_mfma_f32_16x16x32_bf16(qf0, kf0, s, 0, 0, 0);
            s = __builtin_amdgcn_mfma_f32_16x16x32_bf16(qf1, kf1, s, 0, 0, 0);
            sc[j] = s;
        }

        const bool maskt = (kv0 == q0);  // only the diagonal tile needs masking
        for (int j = 0; j < 4; j++)
            for (int r = 0; r < 4; r++) {
                float v = sc[j][r] * 0.125f;  // 1/sqrt(64)
                if (maskt) {
                    int col = kv0 + j * 16 + l16;
                    int row = q0 + wave * 16 + quad * 4 + r;
                    if (col > row) v = -1e30f;
                }
                sc[j][r] = v;
            }

        // online softmax, per C-layout row (quad*4+r); reduce across the 16 lanes of the quad
        float alpha_r[4];
        for (int r = 0; r < 4; r++) {
            float mx = fmaxf(fmaxf(sc[0][r], sc[1][r]), fmaxf(sc[2][r], sc[3][r]));
            for (int off = 1; off < 16; off <<= 1) mx = fmaxf(mx, __shfl_xor(mx, off, 64));
            float mnew = fmaxf(mrun[r], mx);
            float alpha = exp2f((mrun[r] - mnew) * L2E);
            float rs = 0.f;
            for (int j = 0; j < 4; j++) {
                float p = exp2f((sc[j][r] - mnew) * L2E);
                sc[j][r] = p;
                rs += p;
            }
            for (int off = 1; off < 16; off <<= 1) rs += __shfl_xor(rs, off, 64);
            mrun[r] = mnew;
            lrun[r] = lrun[r] * alpha + rs;
            alpha_r[r] = alpha;
        }
        for (int j = 0; j < 4; j++)
            for (int r = 0; r < 4; r++) ao[j][r] *= alpha_r[r];

        // P: C-layout regs -> LDS -> A-layout frags (bf16)
        unsigned short* Pw = Ps[wave];
        for (int j = 0; j < 4; j++)
            for (int r = 0; r < 4; r++)
                Pw[(quad * 4 + r) * 72 + j * 16 + l16] = f2bf(sc[j][r]);
        __syncthreads();

        // O += P V
        for (int ko = 0; ko < 64; ko += 32) {
            bf16x8 pf = *reinterpret_cast<const bf16x8*>(Pw + l16 * 72 + ko + quad * 8);
            for (int j = 0; j < 4; j++) {
                bf16x8 vf;
                for (int t = 0; t < 8; t++)
                    vf[t] = *reinterpret_cast<const __bf16*>(Vs + (ko + quad * 8 + t) * 66 + j * 16 + l16);
                ao[j] = __builtin_amdgcn_mfma_f32_16x16x32_bf16(pf, vf, ao[j], 0, 0, 0);
            }
        }
    }

    // epilogue: O /= l, merge heads into [B*S, D] bf16
    const int b = bh >> 4, h = bh & 15;
    for (int j = 0; j < 4; j++)
        for (int r = 0; r < 4; r++) {
            int srow = q0 + wave * 16 + quad * 4 + r;
            float ov = ao[j][r] / lrun[r];
            attn[((size_t)(b * SS + srow)) * DD + h * DKK + j * 16 + l16] = f2bf(ov);
        }
}

// ---------------- launch ----------------
extern "C" void kernel_launch(void* const* d_in, const int* in_sizes, int n_in,
                              void* d_out, int out_size, void* d_ws, size_t ws_size,
                              hipStream_t stream) {
    const float* x  = (const float*)d_in[0];
    const float* Wq = (const float*)d_in[1];
    const float* Wk = (const float*)d_in[2];
    const float* Wv = (const float*)d_in[3];
    const float* Wo = (const float*)d_in[4];

    char* ws = (char*)d_ws;
    const size_t MB = 1u << 20;
    unsigned short* xb    = (unsigned short*)(ws);             // 8 MB  [4096,1024] bf16
    unsigned short* Wqb   = (unsigned short*)(ws + 8  * MB);   // 2 MB each
    unsigned short* Wkb   = (unsigned short*)(ws + 10 * MB);
    unsigned short* Wvb   = (unsigned short*)(ws + 12 * MB);
    unsigned short* Wob   = (unsigned short*)(ws + 14 * MB);
    unsigned short* Qbuf  = (unsigned short*)(ws + 16 * MB);   // 8 MB [B,H,S,DK]
    unsigned short* Kbuf  = (unsigned short*)(ws + 24 * MB);
    unsigned short* Vbuf  = (unsigned short*)(ws + 32 * MB);
    unsigned short* attnb = (unsigned short*)(ws + 40 * MB);   // 8 MB [B*S, D]

    const int nx = MM * DD;       // 4194304
    const int nw = DD * DD;       // 1048576
    cast_f32_bf16<<<nx / 1024, 256, 0, stream>>>(x,  xb,  nx);
    cast_f32_bf16<<<nw / 1024, 256, 0, stream>>>(Wq, Wqb, nw);
    cast_f32_bf16<<<nw / 1024, 256, 0, stream>>>(Wk, Wkb, nw);
    cast_f32_bf16<<<nw / 1024, 256, 0, stream>>>(Wv, Wvb, nw);
    cast_f32_bf16<<<nw / 1024, 256, 0, stream>>>(Wo, Wob, nw);

    dim3 gg(DD / 128, MM / 128);   // (8, 32)
    gemm_bt<<<gg, 256, 0, stream>>>(xb, Wqb, (void*)Qbuf, 0);  // Q + RoPE
    gemm_bt<<<gg, 256, 0, stream>>>(xb, Wkb, (void*)Kbuf, 1);  // K + RoPE
    gemm_bt<<<gg, 256, 0, stream>>>(xb, Wvb, (void*)Vbuf, 2);  // V

    attn_kernel<<<dim3(SS / 64, BB * HH), 256, 0, stream>>>(Qbuf, Kbuf, Vbuf, attnb);

    gemm_bt<<<gg, 256, 0, stream>>>(attnb, Wob, d_out, 3);     // out projection, fp32
}

// Round 2
// 322.948 us; speedup vs baseline: 1.1332x; 1.1332x over previous
//
#include <hip/hip_runtime.h>
#include <hip/hip_bf16.h>
#include <cstdint>
#include <cstddef>

// Problem constants (B,S,D,H = 2,2048,1024,16; DK=64)
#define BB 2
#define SS 2048
#define DD 1024
#define HH 16
#define DKK 64
#define MM (BB*SS)   // 4096 rows for the projection GEMMs

typedef __bf16 bf16x8 __attribute__((ext_vector_type(8)));
typedef float  f32x4  __attribute__((ext_vector_type(4)));

__device__ __forceinline__ unsigned short f2bf(float f) {
    unsigned u = __float_as_uint(f);
    u += 0x7FFF + ((u >> 16) & 1);   // round-to-nearest-even
    return (unsigned short)(u >> 16);
}

// async global->LDS, 16B per lane. LDS side must be wave-uniform base + lane*16.
__device__ __forceinline__ void gld_lds16(const void* g, void* l) {
    __builtin_amdgcn_global_load_lds(
        (const __attribute__((address_space(1))) unsigned int*)g,
        (__attribute__((address_space(3))) unsigned int*)l, 16, 0, 0);
}

// ---------------- fp32 -> bf16 cast ----------------
__global__ __launch_bounds__(256) void cast_f32_bf16(const float* __restrict__ src,
                                                     unsigned short* __restrict__ dst, int n) {
    int i = (blockIdx.x * 256 + threadIdx.x) * 4;
    if (i < n) {
        float4 v = *reinterpret_cast<const float4*>(src + i);
        ushort4 o;
        o.x = f2bf(v.x); o.y = f2bf(v.y); o.z = f2bf(v.z); o.w = f2bf(v.w);
        *reinterpret_cast<ushort4*>(dst + i) = o;
    }
}

// ---------------- GEMM: C[m,n] = sum_k A[m,k] * W[n,k]  (both bf16 row-major) ----------------
// mode 0/1: RoPE epilogue, write bf16 [B,H,S,DK]  (Q / K)
// mode 2  : write bf16 TRANSPOSED [B,H,DK,S]      (V -> Vt, so attention can vector-read B-frags)
// mode 3  : write fp32 [M,N] flat                 (output projection)
// LDS tiles are lane-linear (for global_load_lds); the 8-short group column is
// XOR-swizzled by (row&3) on the GLOBAL side so frag reads are ~2-way (free).
__global__ __launch_bounds__(256) void gemm_bt(const unsigned short* __restrict__ A,
                                               const unsigned short* __restrict__ W,
                                               void* __restrict__ outp, int mode) {
    __shared__ unsigned short As[128 * 32];
    __shared__ unsigned short Ws[128 * 32];
    const int tid  = threadIdx.x;
    const int wave = tid >> 6, lane = tid & 63;
    const int quad = lane >> 4, l16 = lane & 15;
    const int wm = wave >> 1, wn = wave & 1;
    const int m0 = blockIdx.y * 128, n0 = blockIdx.x * 128;
    const int K = DD;
    const int sw3 = l16 & 3;

    f32x4 acc[4][4];
    for (int i = 0; i < 4; i++)
        for (int j = 0; j < 4; j++) acc[i][j] = f32x4{0.f, 0.f, 0.f, 0.f};

    for (int k0 = 0; k0 < K; k0 += 32) {
        __syncthreads();
        for (int c = tid; c < 512; c += 256) {
            int row = c >> 2, g = c & 3;
            int gc = ((g ^ (row & 3)) << 3);
            gld_lds16(A + (size_t)(m0 + row) * K + k0 + gc, As + c * 8);
            gld_lds16(W + (size_t)(n0 + row) * K + k0 + gc, Ws + c * 8);
        }
        __syncthreads();   // drains vmcnt (global_load_lds) for all waves
        bf16x8 af[4], bfb[4];
        for (int i = 0; i < 4; i++)
            af[i] = *reinterpret_cast<const bf16x8*>(As + (wm * 64 + i * 16 + l16) * 32 + ((quad ^ sw3) << 3));
        for (int j = 0; j < 4; j++)
            bfb[j] = *reinterpret_cast<const bf16x8*>(Ws + (wn * 64 + j * 16 + l16) * 32 + ((quad ^ sw3) << 3));
        for (int i = 0; i < 4; i++)
            for (int j = 0; j < 4; j++)
                acc[i][j] = __builtin_amdgcn_mfma_f32_16x16x32_bf16(af[i], bfb[j], acc[i][j], 0, 0, 0);
    }

    const float L2T_OVER_DK = 13.287712379549449f / 64.0f;  // log2(10000)/64
    if (mode == 3) {
        float* Co = (float*)outp;
        for (int i = 0; i < 4; i++) {
            int mrow = m0 + wm * 64 + i * 16 + quad * 4;
            for (int j = 0; j < 4; j++) {
                int ncol = n0 + wn * 64 + j * 16 + l16;
                for (int r = 0; r < 4; r++)
                    Co[(size_t)(mrow + r) * DD + ncol] = acc[i][j][r];
            }
        }
    } else if (mode == 2) {
        // V: write transposed Vt[b][h][dk][s] so attention B-frags are contiguous.
        __syncthreads();                       // other waves done reading As
        unsigned short* T = As + wave * 1024;  // per-wave 16x16 scratch, stride 17
        unsigned short* Co = (unsigned short*)outp;
        const int dkl = lane >> 2, s4 = (lane & 3) * 4;
        for (int i = 0; i < 4; i++) {
            int ms0 = m0 + wm * 64 + i * 16;
            for (int j = 0; j < 4; j++) {
                int nc0 = n0 + wn * 64 + j * 16;
                for (int r = 0; r < 4; r++)
                    T[(quad * 4 + r) * 17 + l16] = f2bf(acc[i][j][r]);
                // same-wave LDS RAW: compiler orders via lgkmcnt; no barrier needed
                ushort4 o;
                o.x = T[(s4 + 0) * 17 + dkl];
                o.y = T[(s4 + 1) * 17 + dkl];
                o.z = T[(s4 + 2) * 17 + dkl];
                o.w = T[(s4 + 3) * 17 + dkl];
                int ncol = nc0 + dkl;
                int h = ncol >> 6, dk = ncol & 63;
                int m = ms0 + s4;
                int b = m >> 11, s = m & 2047;
                *reinterpret_cast<ushort4*>(Co + ((size_t)((b * HH + h) * DKK + dk)) * SS + s) = o;
            }
        }
    } else {
        unsigned short* Co = (unsigned short*)outp;
        for (int i = 0; i < 4; i++) {
            int mrow = m0 + wm * 64 + i * 16 + quad * 4;
            for (int j = 0; j < 4; j++) {
                int ncol = n0 + wn * 64 + j * 16 + l16;
                int h = ncol >> 6, dk = ncol & 63;
                for (int r = 0; r < 4; r++) {
                    int m = mrow + r;
                    int b = m >> 11, s = m & 2047;
                    float v = acc[i][j][r];
                    float partner = __shfl_xor(v, 1, 64);  // lane^1 holds dk^1 (RoPE pair)
                    float inv_freq = exp2f(-(float)(dk & ~1) * L2T_OVER_DK);
                    float ang = (float)s * inv_freq;
                    float sn, cs;
                    __sincosf(ang, &sn, &cs);
                    float outv = v * cs + ((dk & 1) ? partner : -partner) * sn;
                    Co[((size_t)(b * HH + h) * SS + s) * DKK + dk] = f2bf(outv);
                }
            }
        }
    }
}

// ---------------- Flash attention (causal, online softmax) ----------------
// grid: (S/64 q-tiles, B*H). 256 thr = 4 waves; wave w owns q rows [q0+16w, q0+16w+16).
// K and Vt tiles staged via global_load_lds (lane-linear LDS, XOR-swizzled global source).
__global__ __launch_bounds__(256) void attn_kernel(const unsigned short* __restrict__ Qb,
                                                   const unsigned short* __restrict__ Kb,
                                                   const unsigned short* __restrict__ Vtb,
                                                   unsigned short* __restrict__ attn) {
    __shared__ unsigned short Ks[64 * 64];     // K tile  [kv][d], groups swizzled
    __shared__ unsigned short Vs[64 * 64];     // Vt tile [d][kv], groups swizzled
    __shared__ unsigned short Ps[4][16 * 72];  // per-wave P tile (C-layout -> A-layout)

    const int tid  = threadIdx.x;
    const int wave = tid >> 6, lane = tid & 63;
    const int quad = lane >> 4, l16 = lane & 15;
    const int q0 = (gridDim.x - 1 - blockIdx.x) * 64;  // heavy blocks dispatch first
    const int bh = blockIdx.y;
    const int sw = l16 & 7;

    const unsigned short* Qg = Qb  + (size_t)bh * SS * DKK;
    const unsigned short* Kg = Kb  + (size_t)bh * SS * DKK;
    const unsigned short* Vg = Vtb + (size_t)bh * DKK * SS;  // [dk][s]

    const int qrow = q0 + wave * 16 + l16;  // A-operand: m = lane&15
    bf16x8 qf0 = *reinterpret_cast<const bf16x8*>(Qg + (size_t)qrow * DKK + quad * 8);
    bf16x8 qf1 = *reinterpret_cast<const bf16x8*>(Qg + (size_t)qrow * DKK + 32 + quad * 8);

    f32x4 ao[4];
    for (int j = 0; j < 4; j++) ao[j] = f32x4{0.f, 0.f, 0.f, 0.f};
    float mrun[4] = {-1e30f, -1e30f, -1e30f, -1e30f};
    float lrun[4] = {0.f, 0.f, 0.f, 0.f};
    const float L2E = 1.4426950408889634f;

    for (int kv0 = 0; kv0 <= q0; kv0 += 64) {
        __syncthreads();   // previous iteration's frag reads of Ks/Vs done
        for (int c = tid; c < 512; c += 256) {
            int row = c >> 3, g = c & 7;
            int gc = ((g ^ (row & 7)) << 3);
            gld_lds16(Kg + (size_t)(kv0 + row) * DKK + gc, Ks + c * 8);
            gld_lds16(Vg + (size_t)row * SS + kv0 + gc, Vs + c * 8);
        }
        __syncthreads();   // drains vmcnt for the LDS-DMA

        // S = Q K^T (16x64 per wave). B-frag: K[kv=j*16+l16][d=quad*8(+32)]
        f32x4 sc[4];
        for (int j = 0; j < 4; j++) {
            const unsigned short* kr = Ks + (j * 16 + l16) * 64;
            bf16x8 kf0 = *reinterpret_cast<const bf16x8*>(kr + ((quad ^ sw) << 3));
            bf16x8 kf1 = *reinterpret_cast<const bf16x8*>(kr + (((4 + quad) ^ sw) << 3));
            f32x4 s = f32x4{0.f, 0.f, 0.f, 0.f};
            s = __builtin_amdgcn_mfma_f32_16x16x32_bf16(qf0, kf0, s, 0, 0, 0);
            s = __builtin_amdgcn_mfma_f32_16x16x32_bf16(qf1, kf1, s, 0, 0, 0);
            sc[j] = s;
        }

        const bool maskt = (kv0 == q0);  // only the diagonal tile needs masking
        for (int j = 0; j < 4; j++)
            for (int r = 0; r < 4; r++) {
                float v = sc[j][r] * 0.125f;  // 1/sqrt(64)
                if (maskt) {
                    int col = kv0 + j * 16 + l16;
                    int row = q0 + wave * 16 + quad * 4 + r;
                    if (col > row) v = -1e30f;
                }
                sc[j][r] = v;
            }

        // online softmax, per C-layout row (quad*4+r); reduce across 16 lanes of the quad
        float alpha_r[4];
        for (int r = 0; r < 4; r++) {
            float mx = fmaxf(fmaxf(sc[0][r], sc[1][r]), fmaxf(sc[2][r], sc[3][r]));
            for (int off = 1; off < 16; off <<= 1) mx = fmaxf(mx, __shfl_xor(mx, off, 64));
            float mnew = fmaxf(mrun[r], mx);
            float alpha = exp2f((mrun[r] - mnew) * L2E);
            float rs = 0.f;
            for (int j = 0; j < 4; j++) {
                float p = exp2f((sc[j][r] - mnew) * L2E);
                sc[j][r] = p;
                rs += p;
            }
            for (int off = 1; off < 16; off <<= 1) rs += __shfl_xor(rs, off, 64);
            mrun[r] = mnew;
            lrun[r] = lrun[r] * alpha + rs;
            alpha_r[r] = alpha;
        }
        for (int j = 0; j < 4; j++)
            for (int r = 0; r < 4; r++) ao[j][r] *= alpha_r[r];

        // P: C-layout regs -> per-wave LDS -> A-layout frags (bf16). No barrier:
        // Ps[wave] is private to this wave; compiler orders via lgkmcnt.
        unsigned short* Pw = Ps[wave];
        for (int j = 0; j < 4; j++)
            for (int r = 0; r < 4; r++)
                Pw[(quad * 4 + r) * 72 + j * 16 + l16] = f2bf(sc[j][r]);

        // O += P V.  B-frag: Vt[d=j*16+l16][kv=ko+quad*8]
        for (int ko = 0; ko < 64; ko += 32) {
            bf16x8 pf = *reinterpret_cast<const bf16x8*>(Pw + l16 * 72 + ko + quad * 8);
            int gh = (ko >> 3) + quad;  // global group index 0..7
            for (int j = 0; j < 4; j++) {
                bf16x8 vf = *reinterpret_cast<const bf16x8*>(Vs + (j * 16 + l16) * 64 + ((gh ^ sw) << 3));
                ao[j] = __builtin_amdgcn_mfma_f32_16x16x32_bf16(pf, vf, ao[j], 0, 0, 0);
            }
        }
    }

    // epilogue: O /= l, merge heads into [B*S, D] bf16
    const int b = bh >> 4, h = bh & 15;
    for (int j = 0; j < 4; j++)
        for (int r = 0; r < 4; r++) {
            int srow = q0 + wave * 16 + quad * 4 + r;
            float ov = ao[j][r] / lrun[r];
            attn[((size_t)(b * SS + srow)) * DD + h * DKK + j * 16 + l16] = f2bf(ov);
        }
}

// ---------------- launch ----------------
extern "C" void kernel_launch(void* const* d_in, const int* in_sizes, int n_in,
                              void* d_out, int out_size, void* d_ws, size_t ws_size,
                              hipStream_t stream) {
    const float* x  = (const float*)d_in[0];
    const float* Wq = (const float*)d_in[1];
    const float* Wk = (const float*)d_in[2];
    const float* Wv = (const float*)d_in[3];
    const float* Wo = (const float*)d_in[4];

    char* ws = (char*)d_ws;
    const size_t MB = 1u << 20;
    unsigned short* xb    = (unsigned short*)(ws);             // 8 MB  [4096,1024] bf16
    unsigned short* Wqb   = (unsigned short*)(ws + 8  * MB);   // 2 MB each
    unsigned short* Wkb   = (unsigned short*)(ws + 10 * MB);
    unsigned short* Wvb   = (unsigned short*)(ws + 12 * MB);
    unsigned short* Wob   = (unsigned short*)(ws + 14 * MB);
    unsigned short* Qbuf  = (unsigned short*)(ws + 16 * MB);   // 8 MB [B,H,S,DK]
    unsigned short* Kbuf  = (unsigned short*)(ws + 24 * MB);   // 8 MB [B,H,S,DK]
    unsigned short* Vtbuf = (unsigned short*)(ws + 32 * MB);   // 8 MB [B,H,DK,S] (transposed)
    unsigned short* attnb = (unsigned short*)(ws + 40 * MB);   // 8 MB [B*S, D]

    const int nx = MM * DD;       // 4194304
    const int nw = DD * DD;       // 1048576
    cast_f32_bf16<<<nx / 1024, 256, 0, stream>>>(x,  xb,  nx);
    cast_f32_bf16<<<nw / 1024, 256, 0, stream>>>(Wq, Wqb, nw);
    cast_f32_bf16<<<nw / 1024, 256, 0, stream>>>(Wk, Wkb, nw);
    cast_f32_bf16<<<nw / 1024, 256, 0, stream>>>(Wv, Wvb, nw);
    cast_f32_bf16<<<nw / 1024, 256, 0, stream>>>(Wo, Wob, nw);

    dim3 gg(DD / 128, MM / 128);   // (8, 32)
    gemm_bt<<<gg, 256, 0, stream>>>(xb, Wqb, (void*)Qbuf,  0);  // Q + RoPE
    gemm_bt<<<gg, 256, 0, stream>>>(xb, Wkb, (void*)Kbuf,  1);  // K + RoPE
    gemm_bt<<<gg, 256, 0, stream>>>(xb, Wvb, (void*)Vtbuf, 2);  // V -> Vt

    attn_kernel<<<dim3(SS / 64, BB * HH), 256, 0, stream>>>(Qbuf, Kbuf, Vtbuf, attnb);

    gemm_bt<<<gg, 256, 0, stream>>>(attnb, Wob, d_out, 3);      // out projection, fp32
}

// Round 3
// 226.748 us; speedup vs baseline: 1.6140x; 1.4243x over previous
//
#include <hip/hip_runtime.h>
#include <hip/hip_bf16.h>
#include <cstdint>
#include <cstddef>

// Problem constants (B,S,D,H = 2,2048,1024,16; DK=64)
#define BB 2
#define SS 2048
#define DD 1024
#define HH 16
#define DKK 64
#define MM (BB*SS)   // 4096 rows for the projection GEMMs

typedef __bf16 bf16x8 __attribute__((ext_vector_type(8)));
typedef float  f32x4  __attribute__((ext_vector_type(4)));

__device__ __forceinline__ unsigned short f2bf(float f) {
    unsigned u = __float_as_uint(f);
    u += 0x7FFF + ((u >> 16) & 1);   // round-to-nearest-even
    return (unsigned short)(u >> 16);
}

// async global->LDS, 16B per lane. LDS side must be wave-uniform base + lane*16.
__device__ __forceinline__ void gld_lds16(const void* g, void* l) {
    __builtin_amdgcn_global_load_lds(
        (const __attribute__((address_space(1))) unsigned int*)g,
        (__attribute__((address_space(3))) unsigned int*)l, 16, 0, 0);
}

// manual waitcnt: vmcnt=N, lgkmcnt=15 (no wait), expcnt=7 (no wait)
#define WAIT_VM4() __builtin_amdgcn_s_waitcnt(0x0F74)
#define WAIT_VM0() __builtin_amdgcn_s_waitcnt(0x0F70)
#define BARRIER()  __builtin_amdgcn_s_barrier()

// DPP 16-lane butterfly reduction (pure VALU, no LDS pipe).
// 0xB1=quad_perm{1,0,3,2} (xor1), 0x4E=quad_perm{2,3,0,1} (xor2),
// 0x141=row_half_mirror (crosses 4-groups), 0x140=row_mirror (crosses 8-groups)
#define DPP_F(x, ctrl) __int_as_float(__builtin_amdgcn_mov_dpp(__float_as_int(x), ctrl, 0xF, 0xF, true))
__device__ __forceinline__ float red_max16(float x) {
    x = fmaxf(x, DPP_F(x, 0xB1));
    x = fmaxf(x, DPP_F(x, 0x4E));
    x = fmaxf(x, DPP_F(x, 0x141));
    x = fmaxf(x, DPP_F(x, 0x140));
    return x;
}
__device__ __forceinline__ float red_sum16(float x) {
    x += DPP_F(x, 0xB1);
    x += DPP_F(x, 0x4E);
    x += DPP_F(x, 0x141);
    x += DPP_F(x, 0x140);
    return x;
}

// ---------------- fused fp32 -> bf16 cast (x + 4 weights, one launch) ----------------
// wb holds [Wq|Wk|Wv|Wo] bf16, 1M elements each.
__global__ __launch_bounds__(256) void cast_all(const float* __restrict__ x,
                                                const float* __restrict__ wq,
                                                const float* __restrict__ wk,
                                                const float* __restrict__ wv,
                                                const float* __restrict__ wo,
                                                unsigned short* __restrict__ xb,
                                                unsigned short* __restrict__ wb) {
    int i = (blockIdx.x * 256 + threadIdx.x) * 4;
    const float* src;
    unsigned short* dst;
    if (i < MM * DD) { src = x + i; dst = xb + i; }
    else {
        int e = i - MM * DD;
        int r = e >> 20;                    // 1M elements per weight
        const float* s0 = (r == 0) ? wq : (r == 1) ? wk : (r == 2) ? wv : wo;
        src = s0 + (e & ((1 << 20) - 1));
        dst = wb + e;
    }
    float4 v = *reinterpret_cast<const float4*>(src);
    ushort4 o;
    o.x = f2bf(v.x); o.y = f2bf(v.y); o.z = f2bf(v.z); o.w = f2bf(v.w);
    *reinterpret_cast<ushort4*>(dst) = o;
}

// ---------------- fused QKV GEMM: C[m,n] = sum_k A[m,k] * W[n,k], N=3072 ----------------
// region 0 (n<1024): Q + RoPE -> Qo [B,H,S,DK]
// region 1         : K + RoPE -> Ko [B,H,S,DK]
// region 2         : V transposed -> Vto [B,H,DK,S]
__global__ __launch_bounds__(256) void gemm_qkv(const unsigned short* __restrict__ A,
                                                const unsigned short* __restrict__ W,
                                                unsigned short* __restrict__ Qo,
                                                unsigned short* __restrict__ Ko,
                                                unsigned short* __restrict__ Vto) {
    __shared__ unsigned short As[128 * 32];
    __shared__ unsigned short Ws[128 * 32];
    const int tid  = threadIdx.x;
    const int wave = tid >> 6, lane = tid & 63;
    const int quad = lane >> 4, l16 = lane & 15;
    const int wm = wave >> 1, wn = wave & 1;
    const int m0 = blockIdx.y * 128, n0 = blockIdx.x * 128;
    const int sw3 = l16 & 3;

    f32x4 acc[4][4];
    for (int i = 0; i < 4; i++)
        for (int j = 0; j < 4; j++) acc[i][j] = f32x4{0.f, 0.f, 0.f, 0.f};

    for (int k0 = 0; k0 < DD; k0 += 32) {
        __syncthreads();
        for (int c = tid; c < 512; c += 256) {
            int row = c >> 2, g = c & 3;
            int gc = ((g ^ (row & 3)) << 3);
            gld_lds16(A + (size_t)(m0 + row) * DD + k0 + gc, As + c * 8);
            gld_lds16(W + (size_t)(n0 + row) * DD + k0 + gc, Ws + c * 8);
        }
        __syncthreads();
        bf16x8 af[4], bfb[4];
        for (int i = 0; i < 4; i++)
            af[i] = *reinterpret_cast<const bf16x8*>(As + (wm * 64 + i * 16 + l16) * 32 + ((quad ^ sw3) << 3));
        for (int j = 0; j < 4; j++)
            bfb[j] = *reinterpret_cast<const bf16x8*>(Ws + (wn * 64 + j * 16 + l16) * 32 + ((quad ^ sw3) << 3));
        for (int i = 0; i < 4; i++)
            for (int j = 0; j < 4; j++)
                acc[i][j] = __builtin_amdgcn_mfma_f32_16x16x32_bf16(af[i], bfb[j], acc[i][j], 0, 0, 0);
    }

    const int region = n0 >> 10;
    const float L2T_OVER_DK = 13.287712379549449f / 64.0f;  // log2(10000)/64
    if (region < 2) {
        unsigned short* Co = region ? Ko : Qo;
        for (int i = 0; i < 4; i++) {
            int mrow = m0 + wm * 64 + i * 16 + quad * 4;
            for (int j = 0; j < 4; j++) {
                int nc = (n0 + wn * 64 + j * 16 + l16) & 1023;
                int h = nc >> 6, dk = nc & 63;
                for (int r = 0; r < 4; r++) {
                    int m = mrow + r;
                    int b = m >> 11, s = m & 2047;
                    float v = acc[i][j][r];
                    float partner = __shfl_xor(v, 1, 64);  // lane^1 holds dk^1 (RoPE pair)
                    float inv_freq = exp2f(-(float)(dk & ~1) * L2T_OVER_DK);
                    float ang = (float)s * inv_freq;
                    float sn, cs;
                    __sincosf(ang, &sn, &cs);
                    float outv = v * cs + ((dk & 1) ? partner : -partner) * sn;
                    Co[((size_t)(b * HH + h) * SS + s) * DKK + dk] = f2bf(outv);
                }
            }
        }
    } else {
        // V: write transposed Vt[b][h][dk][s]
        __syncthreads();                       // other waves done reading As
        unsigned short* T = As + wave * 1024;  // per-wave 16x16 scratch, stride 17
        const int dkl = lane >> 2, s4 = (lane & 3) * 4;
        for (int i = 0; i < 4; i++) {
            int ms0 = m0 + wm * 64 + i * 16;
            for (int j = 0; j < 4; j++) {
                int nc0 = n0 + wn * 64 + j * 16;
                for (int r = 0; r < 4; r++)
                    T[(quad * 4 + r) * 17 + l16] = f2bf(acc[i][j][r]);
                // same-wave LDS RAW: compiler orders via lgkmcnt
                ushort4 o;
                o.x = T[(s4 + 0) * 17 + dkl];
                o.y = T[(s4 + 1) * 17 + dkl];
                o.z = T[(s4 + 2) * 17 + dkl];
                o.w = T[(s4 + 3) * 17 + dkl];
                int nc = (nc0 + dkl) & 1023;
                int h = nc >> 6, dk = nc & 63;
                int m = ms0 + s4;
                int b = m >> 11, s = m & 2047;
                *reinterpret_cast<ushort4*>(Vto + ((size_t)((b * HH + h) * DKK + dk)) * SS + s) = o;
            }
        }
    }
}

// ---------------- out-projection GEMM: 64x128 tile (grid 512 = 2 blocks/CU) ----------------
__global__ __launch_bounds__(256) void gemm_out(const unsigned short* __restrict__ A,
                                                const unsigned short* __restrict__ W,
                                                float* __restrict__ C) {
    __shared__ unsigned short As[64 * 32];
    __shared__ unsigned short Ws[128 * 32];
    const int tid  = threadIdx.x;
    const int wave = tid >> 6, lane = tid & 63;
    const int quad = lane >> 4, l16 = lane & 15;
    const int wm = wave >> 1, wn = wave & 1;
    const int m0 = blockIdx.y * 64, n0 = blockIdx.x * 128;
    const int sw3 = l16 & 3;

    f32x4 acc[2][4];
    for (int i = 0; i < 2; i++)
        for (int j = 0; j < 4; j++) acc[i][j] = f32x4{0.f, 0.f, 0.f, 0.f};

    for (int k0 = 0; k0 < DD; k0 += 32) {
        __syncthreads();
        {
            int row = tid >> 2, g = tid & 3;
            int gc = ((g ^ (row & 3)) << 3);
            gld_lds16(A + (size_t)(m0 + row) * DD + k0 + gc, As + tid * 8);
        }
        for (int c = tid; c < 512; c += 256) {
            int row = c >> 2, g = c & 3;
            int gc = ((g ^ (row & 3)) << 3);
            gld_lds16(W + (size_t)(n0 + row) * DD + k0 + gc, Ws + c * 8);
        }
        __syncthreads();
        bf16x8 af[2], bfb[4];
        for (int i = 0; i < 2; i++)
            af[i] = *reinterpret_cast<const bf16x8*>(As + (wm * 32 + i * 16 + l16) * 32 + ((quad ^ sw3) << 3));
        for (int j = 0; j < 4; j++)
            bfb[j] = *reinterpret_cast<const bf16x8*>(Ws + (wn * 64 + j * 16 + l16) * 32 + ((quad ^ sw3) << 3));
        for (int i = 0; i < 2; i++)
            for (int j = 0; j < 4; j++)
                acc[i][j] = __builtin_amdgcn_mfma_f32_16x16x32_bf16(af[i], bfb[j], acc[i][j], 0, 0, 0);
    }

    for (int i = 0; i < 2; i++) {
        int mrow = m0 + wm * 32 + i * 16 + quad * 4;
        for (int j = 0; j < 4; j++) {
            int ncol = n0 + wn * 64 + j * 16 + l16;
            for (int r = 0; r < 4; r++)
                C[(size_t)(mrow + r) * DD + ncol] = acc[i][j][r];
        }
    }
}

// ---------------- Flash attention: paired q-tiles + async ping-pong prefetch ----------------
// Block t handles q-tiles t (lo) and 31-t (hi): every block = exactly 33 tile-computations,
// each staged K/V tile feeds 2 tiles of MFMA. grid (16, B*H).
__global__ __launch_bounds__(256) void attn_kernel(const unsigned short* __restrict__ Qb,
                                                   const unsigned short* __restrict__ Kb,
                                                   const unsigned short* __restrict__ Vtb,
                                                   unsigned short* __restrict__ attn) {
    __shared__ unsigned short K0s[64 * 64], V0s[64 * 64];   // ping
    __shared__ unsigned short K1s[64 * 64], V1s[64 * 64];   // pong
    __shared__ unsigned short Ps[4][16 * 72];               // per-wave P round-trip

    const int tid  = threadIdx.x;
    const int wave = tid >> 6, lane = tid & 63;
    const int quad = lane >> 4, l16 = lane & 15;
    const int t  = blockIdx.x;            // 0..15 (heaviest first)
    const int bh = blockIdx.y;
    const int sw = l16 & 7;
    const int qlo = t * 64, qhi = (31 - t) * 64;
    const int nIter = 32 - t;

    const unsigned short* Qg = Qb  + (size_t)bh * SS * DKK;
    const unsigned short* Kg = Kb  + (size_t)bh * SS * DKK;
    const unsigned short* Vg = Vtb + (size_t)bh * DKK * SS;  // [dk][s]

    bf16x8 qL0 = *reinterpret_cast<const bf16x8*>(Qg + (size_t)(qlo + wave * 16 + l16) * DKK + quad * 8);
    bf16x8 qL1 = *reinterpret_cast<const bf16x8*>(Qg + (size_t)(qlo + wave * 16 + l16) * DKK + 32 + quad * 8);
    bf16x8 qH0 = *reinterpret_cast<const bf16x8*>(Qg + (size_t)(qhi + wave * 16 + l16) * DKK + quad * 8);
    bf16x8 qH1 = *reinterpret_cast<const bf16x8*>(Qg + (size_t)(qhi + wave * 16 + l16) * DKK + 32 + quad * 8);

    f32x4 aoL[4], aoH[4];
    float mL[4], lL[4], mH[4], lH[4];
    for (int j = 0; j < 4; j++) { aoL[j] = f32x4{0.f,0.f,0.f,0.f}; aoH[j] = f32x4{0.f,0.f,0.f,0.f}; }
    for (int r = 0; r < 4; r++) { mL[r] = mH[r] = -1e30f; lL[r] = lH[r] = 0.f; }

    auto stage = [&](int it, unsigned short* Kd, unsigned short* Vd) {
        const int kv0 = it * 64;
        for (int c = tid; c < 512; c += 256) {       // 2 c-values/thread -> 4 loads/wave total
            int row = c >> 3, g = c & 7;
            int gc = ((g ^ (row & 7)) << 3);
            gld_lds16(Kg + (size_t)(kv0 + row) * DKK + gc, Kd + c * 8);
            gld_lds16(Vg + (size_t)row * SS + kv0 + gc, Vd + c * 8);
        }
    };

    const float C1 = 0.18033688011112042f;  // log2(e) / sqrt(DK)=8  (scale folded into exp2)

    auto do_tile = [&](const unsigned short* Kd, const unsigned short* Vd,
                       bf16x8 q0f, bf16x8 q1f, bool diag,
                       f32x4* ao, float* mr, float* lr) {
        f32x4 sc[4];
        for (int j = 0; j < 4; j++) {
            const unsigned short* kr = Kd + (j * 16 + l16) * 64;
            bf16x8 kf0 = *reinterpret_cast<const bf16x8*>(kr + ((quad ^ sw) << 3));
            bf16x8 kf1 = *reinterpret_cast<const bf16x8*>(kr + (((4 + quad) ^ sw) << 3));
            f32x4 s = f32x4{0.f, 0.f, 0.f, 0.f};
            s = __builtin_amdgcn_mfma_f32_16x16x32_bf16(q0f, kf0, s, 0, 0, 0);
            s = __builtin_amdgcn_mfma_f32_16x16x32_bf16(q1f, kf1, s, 0, 0, 0);
            sc[j] = s;
        }
        if (diag) {   // only the diagonal tile masks; local row/col suffice
            for (int j = 0; j < 4; j++) {
                int lcol = j * 16 + l16;
                for (int r = 0; r < 4; r++) {
                    int lrow = wave * 16 + quad * 4 + r;
                    if (lcol > lrow) sc[j][r] = -1e30f;
                }
            }
        }
        float ar[4];
        for (int r = 0; r < 4; r++) {
            float mx = fmaxf(fmaxf(sc[0][r], sc[1][r]), fmaxf(sc[2][r], sc[3][r]));
            mx = red_max16(mx);
            float mnew = fmaxf(mr[r], mx);
            float alpha = exp2f((mr[r] - mnew) * C1);
            float nb = -mnew * C1;
            float rs = 0.f;
            for (int j = 0; j < 4; j++) {
                float p = exp2f(fmaf(sc[j][r], C1, nb));
                sc[j][r] = p;
                rs += p;
            }
            rs = red_sum16(rs);
            mr[r] = mnew;
            lr[r] = lr[r] * alpha + rs;
            ar[r] = alpha;
        }
        for (int j = 0; j < 4; j++)
            for (int r = 0; r < 4; r++) ao[j][r] *= ar[r];

        // P: C-layout -> per-wave LDS -> A-layout (same-wave RAW, lgkm-ordered)
        unsigned short* Pw = Ps[wave];
        for (int j = 0; j < 4; j++)
            for (int r = 0; r < 4; r++)
                Pw[(quad * 4 + r) * 72 + j * 16 + l16] = f2bf(sc[j][r]);

        for (int ko = 0; ko < 64; ko += 32) {
            bf16x8 pf = *reinterpret_cast<const bf16x8*>(Pw + l16 * 72 + ko + quad * 8);
            int gh = (ko >> 3) + quad;
            for (int j = 0; j < 4; j++) {
                bf16x8 vf = *reinterpret_cast<const bf16x8*>(Vd + (j * 16 + l16) * 64 + ((gh ^ sw) << 3));
                ao[j] = __builtin_amdgcn_mfma_f32_16x16x32_bf16(pf, vf, ao[j], 0, 0, 0);
            }
        }
    };

    // ping-pong K-loop: raw barriers + vmcnt(4) so next tile's LDS-DMA stays in
    // flight across the whole compute section (never vmcnt(0) mid-loop).
    stage(0, K0s, V0s);
    int it = 0;
    while (true) {
        BARRIER();                                    // all waves done with pong
        if (it + 1 < nIter) { stage(it + 1, K1s, V1s); WAIT_VM4(); } else WAIT_VM0();
        BARRIER();                                    // ping tile visible to all
        do_tile(K0s, V0s, qH0, qH1, it == nIter - 1, aoH, mH, lH);
        if (it <= t) do_tile(K0s, V0s, qL0, qL1, it == t, aoL, mL, lL);
        if (++it >= nIter) break;

        BARRIER();
        if (it + 1 < nIter) { stage(it + 1, K0s, V0s); WAIT_VM4(); } else WAIT_VM0();
        BARRIER();
        do_tile(K1s, V1s, qH0, qH1, it == nIter - 1, aoH, mH, lH);
        if (it <= t) do_tile(K1s, V1s, qL0, qL1, it == t, aoL, mL, lL);
        if (++it >= nIter) break;
    }

    const int b = bh >> 4, h = bh & 15;
    for (int r = 0; r < 4; r++) {
        float invL = 1.0f / lL[r];
        float invH = 1.0f / lH[r];
        int srL = qlo + wave * 16 + quad * 4 + r;
        int srH = qhi + wave * 16 + quad * 4 + r;
        for (int j = 0; j < 4; j++) {
            attn[((size_t)(b * SS + srL)) * DD + h * DKK + j * 16 + l16] = f2bf(aoL[j][r] * invL);
            attn[((size_t)(b * SS + srH)) * DD + h * DKK + j * 16 + l16] = f2bf(aoH[j][r] * invH);
        }
    }
}

// ---------------- launch ----------------
extern "C" void kernel_launch(void* const* d_in, const int* in_sizes, int n_in,
                              void* d_out, int out_size, void* d_ws, size_t ws_size,
                              hipStream_t stream) {
    const float* x  = (const float*)d_in[0];
    const float* Wq = (const float*)d_in[1];
    const float* Wk = (const float*)d_in[2];
    const float* Wv = (const float*)d_in[3];
    const float* Wo = (const float*)d_in[4];

    char* ws = (char*)d_ws;
    const size_t MB = 1u << 20;
    unsigned short* xb    = (unsigned short*)(ws);             // 8 MB  [4096,1024] bf16
    unsigned short* wb    = (unsigned short*)(ws + 8  * MB);   // 8 MB  [Wq|Wk|Wv|Wo] bf16
    unsigned short* Qbuf  = (unsigned short*)(ws + 16 * MB);   // 8 MB [B,H,S,DK]
    unsigned short* Kbuf  = (unsigned short*)(ws + 24 * MB);   // 8 MB [B,H,S,DK]
    unsigned short* Vtbuf = (unsigned short*)(ws + 32 * MB);   // 8 MB [B,H,DK,S]
    unsigned short* attnb = (unsigned short*)(ws + 40 * MB);   // 8 MB [B*S, D]

    // one cast launch: x (4M) + 4 weights (4M) = 8M elements, 4/thread
    cast_all<<<8192, 256, 0, stream>>>(x, Wq, Wk, Wv, Wo, xb, wb);

    // fused QKV projection: N=3072 packed, grid 768 blocks = 3/CU
    gemm_qkv<<<dim3(24, 32), 256, 0, stream>>>(xb, wb, Qbuf, Kbuf, Vtbuf);

    // paired-tile flash attention: grid 512 blocks, uniform 33 tile-units each
    attn_kernel<<<dim3(16, BB * HH), 256, 0, stream>>>(Qbuf, Kbuf, Vtbuf, attnb);

    // out-projection: 64x128 tile, grid 512 = 2/CU, fp32 epilogue
    gemm_out<<<dim3(8, 64), 256, 0, stream>>>(attnb, wb + 3 * 1024 * 1024, (float*)d_out);
}